// Round 1
// baseline (410.350 us; speedup 1.0000x reference)
//
#include <hip/hip_runtime.h>
#include <stdint.h>
#include <math.h>

#define DM 2048
#define NH 16
#define HD 128

typedef __bf16 bf16;
typedef __attribute__((ext_vector_type(8))) __bf16 bf16x8;
typedef __attribute__((ext_vector_type(4))) float f32x4;

__device__ __forceinline__ void gload_lds16(const void* g, void* l) {
  __builtin_amdgcn_global_load_lds(
      (const __attribute__((address_space(1))) void*)g,
      (__attribute__((address_space(3))) void*)l,
      16, 0, 0);
}

// ---------------- fp32 -> bf16 conversion ----------------
__global__ __launch_bounds__(256) void cvt_bf16_k(const float4* __restrict__ src,
                                                  ushort4* __restrict__ dst, int n4) {
  int i = blockIdx.x * 256 + threadIdx.x;
  if (i >= n4) return;
  float4 v = src[i];
  union { bf16 b[4]; ushort4 u; } r;
  r.b[0] = (bf16)v.x; r.b[1] = (bf16)v.y; r.b[2] = (bf16)v.z; r.b[3] = (bf16)v.w;
  dst[i] = r.u;
}

// ---------------- GEMM: C[M,N] = A[M,K] * B[N,K]^T  (m97 structure) ----------------
// M=N=K=2048, 128x128 tile, BK=32, 4 waves, each wave 64x64 (4x4 frags of 16x16)
template <typename OutT>
__global__ __launch_bounds__(256) void gemm128(const bf16* __restrict__ A,
                                               const bf16* __restrict__ Bw,
                                               OutT* __restrict__ C) {
  __shared__ __align__(16) bf16 As[128 * 32];
  __shared__ __align__(16) bf16 Bs[128 * 32];
  const int tid = threadIdx.x;
  const int w = tid >> 6, l = tid & 63;
  const int wr = w >> 1, wc = w & 1;
  const int bx = blockIdx.x, by = blockIdx.y;
  const int lrow = l >> 2, lcol = (l & 3) * 8;
  const int fr = l & 15, fg = l >> 4;
  const bf16* Ag = A + (by * 128 + w * 32 + lrow) * DM + lcol;
  const bf16* Bg = Bw + (bx * 128 + w * 32 + lrow) * DM + lcol;
  bf16* Asw = &As[(w * 32) * 32];
  bf16* Bsw = &Bs[(w * 32) * 32];
  f32x4 acc[4][4] = {};
  for (int kt = 0; kt < DM / 32; ++kt) {
    const int ko = kt * 32;
    gload_lds16(Ag + ko, Asw);
    gload_lds16(Ag + ko + 16 * DM, Asw + 16 * 32);
    gload_lds16(Bg + ko, Bsw);
    gload_lds16(Bg + ko + 16 * DM, Bsw + 16 * 32);
    __syncthreads();
    bf16x8 af[4], bfr[4];
#pragma unroll
    for (int m = 0; m < 4; m++)
      af[m] = *(const bf16x8*)&As[(wr * 64 + m * 16 + fr) * 32 + fg * 8];
#pragma unroll
    for (int n = 0; n < 4; n++)
      bfr[n] = *(const bf16x8*)&Bs[(wc * 64 + n * 16 + fr) * 32 + fg * 8];
#pragma unroll
    for (int m = 0; m < 4; m++)
#pragma unroll
      for (int n = 0; n < 4; n++)
        acc[m][n] = __builtin_amdgcn_mfma_f32_16x16x32_bf16(af[m], bfr[n], acc[m][n], 0, 0, 0);
    __syncthreads();
  }
#pragma unroll
  for (int m = 0; m < 4; m++) {
    const int row0 = by * 128 + wr * 64 + m * 16 + fg * 4;
#pragma unroll
    for (int n = 0; n < 4; n++) {
      const int col = bx * 128 + wc * 64 + n * 16 + fr;
#pragma unroll
      for (int j = 0; j < 4; j++) C[(row0 + j) * DM + col] = (OutT)acc[m][n][j];
    }
  }
}

// ---------------- causal flash attention + fused sigmoid gate ----------------
// grid (S/64, H); 4 waves, wave w owns q rows [qt*64+w*16, +16)
__global__ __launch_bounds__(256) void attn_k(const bf16* __restrict__ Qb,
                                              const bf16* __restrict__ Kb,
                                              const bf16* __restrict__ Vb,
                                              const bf16* __restrict__ GWb,
                                              const float* __restrict__ gbias,
                                              bf16* __restrict__ Gout) {
  __shared__ __align__(16) bf16 Ks[64 * 128];   // [k][d], XOR-swizzled via pre-swizzled source
  __shared__ __align__(16) bf16 Vt[128 * 64];   // [d][k], XOR-swizzled, reg-staged transpose
  __shared__ __align__(16) bf16 Ps[4][16 * 72]; // per-wave P, padded stride 72
  const int qt = blockIdx.x;
  const int h = blockIdx.y;
  const int tid = threadIdx.x;
  const int w = tid >> 6, l = tid & 63;
  const int fr = l & 15, fg = l >> 4;
  const int qbase = qt * 64 + w * 16;

  bf16x8 aq[4];
#pragma unroll
  for (int kt = 0; kt < 4; kt++)
    aq[kt] = *(const bf16x8*)&Qb[(qbase + fr) * DM + h * HD + kt * 32 + fg * 8];

  f32x4 oacc[8] = {};
  float mrow[4], lrow[4];
#pragma unroll
  for (int j = 0; j < 4; j++) { mrow[j] = -INFINITY; lrow[j] = 0.f; }
  const float scale = 0.08838834764831845f;  // 1/sqrt(128)

  for (int t = 0; t <= qt; ++t) {
    const int kv0 = t * 64;
    // ---- stage K via global_load_lds (linear LDS dest, inverse-swizzled global src) ----
    {
      const int r = l >> 4;
      const int c16 = l & 15;
#pragma unroll
      for (int c = 0; c < 4; c++) {
        const int row = w * 16 + c * 4 + r;
        const int src16 = c16 ^ (row & 7);
        gload_lds16(&Kb[(kv0 + row) * DM + h * HD + src16 * 8],
                    &Ks[(w * 16 + c * 4) * 128]);
      }
    }
    // ---- stage V transposed + swizzled (reg path) ----
    {
      const int vr = tid >> 4;
      const int vc16 = tid & 15;
#pragma unroll
      for (int p = 0; p < 4; p++) {
        const int row = p * 16 + vr;  // kv row
        bf16x8 vv = *(const bf16x8*)&Vb[(kv0 + row) * DM + h * HD + vc16 * 8];
#pragma unroll
        for (int jj = 0; jj < 8; jj++) {
          const int d = vc16 * 8 + jj;
          const int byte = d * 128 + ((((row >> 3)) ^ ((d ^ (d >> 3)) & 7)) << 4) + (row & 7) * 2;
          *(bf16*)((char*)Vt + byte) = vv[jj];
        }
      }
    }
    __syncthreads();
    // ---- QK^T : S[16q][64k] per wave ----
    f32x4 sacc[4] = {};
#pragma unroll
    for (int kb = 0; kb < 4; kb++) {
      const int krow = kb * 16 + fr;
      const int swz = krow & 7;
#pragma unroll
      for (int kt = 0; kt < 4; kt++) {
        const int c16 = (kt * 4 + fg) ^ swz;
        const bf16x8 bk = *(const bf16x8*)((const char*)Ks + krow * 256 + c16 * 16);
        sacc[kb] = __builtin_amdgcn_mfma_f32_16x16x32_bf16(aq[kt], bk, sacc[kb], 0, 0, 0);
      }
    }
    // ---- online softmax ----
    float p[4][4], tmax[4];
    const bool diag = (t == qt);
#pragma unroll
    for (int j = 0; j < 4; j++) {
      float mx = -1e30f;
#pragma unroll
      for (int kb = 0; kb < 4; kb++) {
        float s = sacc[kb][j] * scale;
        if (diag && (kv0 + kb * 16 + fr) > (qbase + fg * 4 + j)) s = -1e30f;
        p[kb][j] = s;
        mx = fmaxf(mx, s);
      }
      tmax[j] = mx;
    }
#pragma unroll
    for (int mm = 1; mm < 16; mm <<= 1)
#pragma unroll
      for (int j = 0; j < 4; j++) tmax[j] = fmaxf(tmax[j], __shfl_xor(tmax[j], mm, 64));
    float alpha[4];
#pragma unroll
    for (int j = 0; j < 4; j++) {
      const float mnew = fmaxf(mrow[j], tmax[j]);
      alpha[j] = __expf(mrow[j] - mnew);
      mrow[j] = mnew;
    }
    float rsum[4];
#pragma unroll
    for (int j = 0; j < 4; j++) {
      float sum = 0.f;
#pragma unroll
      for (int kb = 0; kb < 4; kb++) {
        const float e = __expf(p[kb][j] - mrow[j]);
        p[kb][j] = e;
        sum += e;
      }
      rsum[j] = sum;
    }
#pragma unroll
    for (int mm = 1; mm < 16; mm <<= 1)
#pragma unroll
      for (int j = 0; j < 4; j++) rsum[j] += __shfl_xor(rsum[j], mm, 64);
#pragma unroll
    for (int j = 0; j < 4; j++) lrow[j] = lrow[j] * alpha[j] + rsum[j];
#pragma unroll
    for (int db = 0; db < 8; db++)
#pragma unroll
      for (int j = 0; j < 4; j++) oacc[db][j] *= alpha[j];
    // ---- P -> LDS (bf16), per-wave buffer; wave-internal RAW (in-order DS pipe) ----
    bf16* Pw = &Ps[w][0];
#pragma unroll
    for (int kb = 0; kb < 4; kb++)
#pragma unroll
      for (int j = 0; j < 4; j++)
        Pw[(fg * 4 + j) * 72 + kb * 16 + fr] = (bf16)p[kb][j];
    __builtin_amdgcn_wave_barrier();
    // ---- PV ----
#pragma unroll
    for (int kc = 0; kc < 2; kc++) {
      const bf16x8 ap = *(const bf16x8*)&Pw[fr * 72 + kc * 32 + fg * 8];
#pragma unroll
      for (int db = 0; db < 8; db++) {
        const int d = db * 16 + fr;
        const int byte = d * 128 + (((kc * 4 + fg) ^ ((d ^ (d >> 3)) & 7)) << 4);
        const bf16x8 bv = *(const bf16x8*)((const char*)Vt + byte);
        oacc[db] = __builtin_amdgcn_mfma_f32_16x16x32_bf16(ap, bv, oacc[db], 0, 0, 0);
      }
    }
    __syncthreads();
  }
  // ---- epilogue: normalize, fused gate GEMM (reuses Q frags), store bf16 ----
  float rinv[4];
#pragma unroll
  for (int j = 0; j < 4; j++) rinv[j] = 1.0f / lrow[j];
  f32x4 gacc[8] = {};
#pragma unroll
  for (int kt = 0; kt < 4; kt++)
#pragma unroll
    for (int eb = 0; eb < 8; eb++) {
      const bf16x8 bg = *(const bf16x8*)&GWb[(eb * 16 + fr) * HD + kt * 32 + fg * 8];
      gacc[eb] = __builtin_amdgcn_mfma_f32_16x16x32_bf16(aq[kt], bg, gacc[eb], 0, 0, 0);
    }
#pragma unroll
  for (int db = 0; db < 8; db++) {
    const int e = db * 16 + fr;
    const float bias = gbias[e];
    const int col = h * HD + e;
#pragma unroll
    for (int j = 0; j < 4; j++) {
      const float gate = 1.0f / (1.0f + __expf(-(gacc[db][j] + bias)));
      const float o = oacc[db][j] * rinv[j] * gate;
      Gout[(qbase + fg * 4 + j) * DM + col] = (bf16)o;
    }
  }
}

extern "C" void kernel_launch(void* const* d_in, const int* in_sizes, int n_in,
                              void* d_out, int out_size, void* d_ws, size_t ws_size,
                              hipStream_t stream) {
  const float* x  = (const float*)d_in[0];
  const float* qw = (const float*)d_in[1];
  const float* kw = (const float*)d_in[2];
  const float* vw = (const float*)d_in[3];
  const float* ow = (const float*)d_in[4];
  const float* gw = (const float*)d_in[5];
  const float* gb = (const float*)d_in[6];
  float* out = (float*)d_out;

  char* ws = (char*)d_ws;
  const size_t MB = 1024 * 1024;
  bf16* xb  = (bf16*)(ws + 0 * MB);
  bf16* qwb = (bf16*)(ws + 8 * MB);
  bf16* kwb = (bf16*)(ws + 16 * MB);
  bf16* vwb = (bf16*)(ws + 24 * MB);
  bf16* owb = (bf16*)(ws + 32 * MB);
  bf16* gwb = (bf16*)(ws + 40 * MB);
  bf16* Qb  = (bf16*)(ws + 41 * MB);
  bf16* Kb  = (bf16*)(ws + 49 * MB);
  bf16* Vb  = (bf16*)(ws + 57 * MB);
  bf16* Gb  = (bf16*)(ws + 65 * MB);  // total 73 MB

  const int N4 = (DM * DM) / 4;  // 1048576
  cvt_bf16_k<<<N4 / 256, 256, 0, stream>>>((const float4*)x,  (ushort4*)xb,  N4);
  cvt_bf16_k<<<N4 / 256, 256, 0, stream>>>((const float4*)qw, (ushort4*)qwb, N4);
  cvt_bf16_k<<<N4 / 256, 256, 0, stream>>>((const float4*)kw, (ushort4*)kwb, N4);
  cvt_bf16_k<<<N4 / 256, 256, 0, stream>>>((const float4*)vw, (ushort4*)vwb, N4);
  cvt_bf16_k<<<N4 / 256, 256, 0, stream>>>((const float4*)ow, (ushort4*)owb, N4);
  cvt_bf16_k<<<16, 256, 0, stream>>>((const float4*)gw, (ushort4*)gwb, (HD * HD) / 4);

  dim3 g16(16, 16);
  gemm128<bf16><<<g16, 256, 0, stream>>>(xb, qwb, Qb);
  gemm128<bf16><<<g16, 256, 0, stream>>>(xb, kwb, Kb);
  gemm128<bf16><<<g16, 256, 0, stream>>>(xb, vwb, Vb);

  attn_k<<<dim3(DM / 128 * 2, NH), 256, 0, stream>>>(Qb, Kb, Vb, gwb, gb, Gb);

  gemm128<float><<<g16, 256, 0, stream>>>(Gb, owb, out);
}

// Round 2
// 276.486 us; speedup vs baseline: 1.4842x; 1.4842x over previous
//
#include <hip/hip_runtime.h>
#include <stdint.h>
#include <math.h>

#define DM 2048
#define NH 16
#define HD 128
#define LDQ (3 * DM)   // fused QKV row stride

typedef __bf16 bf16;
typedef __attribute__((ext_vector_type(8))) __bf16 bf16x8;
typedef __attribute__((ext_vector_type(4))) float f32x4;
typedef __attribute__((ext_vector_type(2))) unsigned int u32x2;

__device__ __forceinline__ void gload_lds16(const void* g, void* l) {
  __builtin_amdgcn_global_load_lds(
      (const __attribute__((address_space(1))) void*)g,
      (__attribute__((address_space(3))) void*)l,
      16, 0, 0);
}

__device__ __forceinline__ unsigned lds_addr(const void* p) {
  return (unsigned)(size_t)(const __attribute__((address_space(3))) void*)p;
}

template <int OFF>
__device__ __forceinline__ u32x2 tr_read(unsigned va) {
  u32x2 r;
  asm volatile("ds_read_b64_tr_b16 %0, %1 offset:%2"
               : "=v"(r) : "v"(va), "i"(OFF));
  return r;
}

#define TR4(dst, vd)                                        \
  dst[0] = tr_read<0>(vd);   dst[1] = tr_read<512>(vd);     \
  dst[2] = tr_read<1024>(vd); dst[3] = tr_read<1536>(vd);

// ---------------- fp32 -> bf16 conversion (all inputs, one launch) ----------------
__global__ __launch_bounds__(256) void cvt6(const float* xs, const float* qws,
                                            const float* kws, const float* vws,
                                            const float* ows, const float* gws,
                                            ushort* xd, ushort* w3d, ushort* owd,
                                            ushort* gwd) {
  const int y = blockIdx.y;
  const float4* s; ushort4* d; int n = (DM * DM) / 4;
  switch (y) {
    case 0: s = (const float4*)xs;  d = (ushort4*)xd;  break;
    case 1: s = (const float4*)qws; d = (ushort4*)w3d; break;
    case 2: s = (const float4*)kws; d = (ushort4*)(w3d + (size_t)DM * DM); break;
    case 3: s = (const float4*)vws; d = (ushort4*)(w3d + (size_t)2 * DM * DM); break;
    case 4: s = (const float4*)ows; d = (ushort4*)owd; break;
    default: s = (const float4*)gws; d = (ushort4*)gwd; n = (HD * HD) / 4; break;
  }
  int i = blockIdx.x * 256 + threadIdx.x;
  if (i >= n) return;
  float4 v = s[i];
  union { bf16 b[4]; ushort4 u; } r;
  r.b[0] = (bf16)v.x; r.b[1] = (bf16)v.y; r.b[2] = (bf16)v.z; r.b[3] = (bf16)v.w;
  d[i] = r.u;
}

// ---------------- GEMM: C[M,Ncols] = A[M,2048] * B[Ncols,2048]^T ----------------
template <typename OutT>
__global__ __launch_bounds__(256) void gemm128(const bf16* __restrict__ A,
                                               const bf16* __restrict__ Bw,
                                               OutT* __restrict__ C, int ldc) {
  __shared__ __align__(16) bf16 As[128 * 32];
  __shared__ __align__(16) bf16 Bs[128 * 32];
  const int tid = threadIdx.x;
  const int w = tid >> 6, l = tid & 63;
  const int wr = w >> 1, wc = w & 1;
  const int bx = blockIdx.x, by = blockIdx.y;
  const int lrow = l >> 2, lcol = (l & 3) * 8;
  const int fr = l & 15, fg = l >> 4;
  const bf16* Ag = A + (size_t)(by * 128 + w * 32 + lrow) * DM + lcol;
  const bf16* Bg = Bw + (size_t)(bx * 128 + w * 32 + lrow) * DM + lcol;
  bf16* Asw = &As[(w * 32) * 32];
  bf16* Bsw = &Bs[(w * 32) * 32];
  f32x4 acc[4][4] = {};
  for (int kt = 0; kt < DM / 32; ++kt) {
    const int ko = kt * 32;
    gload_lds16(Ag + ko, Asw);
    gload_lds16(Ag + ko + 16 * DM, Asw + 16 * 32);
    gload_lds16(Bg + ko, Bsw);
    gload_lds16(Bg + ko + 16 * DM, Bsw + 16 * 32);
    __syncthreads();
    bf16x8 af[4], bfr[4];
#pragma unroll
    for (int m = 0; m < 4; m++)
      af[m] = *(const bf16x8*)&As[(wr * 64 + m * 16 + fr) * 32 + fg * 8];
#pragma unroll
    for (int n = 0; n < 4; n++)
      bfr[n] = *(const bf16x8*)&Bs[(wc * 64 + n * 16 + fr) * 32 + fg * 8];
#pragma unroll
    for (int m = 0; m < 4; m++)
#pragma unroll
      for (int n = 0; n < 4; n++)
        acc[m][n] = __builtin_amdgcn_mfma_f32_16x16x32_bf16(af[m], bfr[n], acc[m][n], 0, 0, 0);
    __syncthreads();
  }
#pragma unroll
  for (int m = 0; m < 4; m++) {
    const int row0 = by * 128 + wr * 64 + m * 16 + fg * 4;
#pragma unroll
    for (int n = 0; n < 4; n++) {
      const int col = bx * 128 + wc * 64 + n * 16 + fr;
#pragma unroll
      for (int j = 0; j < 4; j++) C[(size_t)(row0 + j) * ldc + col] = (OutT)acc[m][n][j];
    }
  }
}

// ---------------- causal flash attention + fused sigmoid gate ----------------
// swapped QK^T (S^T in regs), in-register P, V via ds_read_b64_tr_b16
// grid (32, 16): qt = 31 - bx (longest first); 4 waves x 16 q-rows
__global__ __launch_bounds__(256, 2) void attn_k(const bf16* __restrict__ QKV,
                                                 const bf16* __restrict__ GWb,
                                                 const float* __restrict__ gbias,
                                                 bf16* __restrict__ Gout) {
  __shared__ __align__(16) bf16 Vs[2][8192];  // [buf][8 dblk][64 k][16 d] = 16KB each
  const int qt = 31 - blockIdx.x;
  const int h = blockIdx.y;
  const int tid = threadIdx.x;
  const int w = tid >> 6, l = tid & 63;
  const int fr = l & 15, fg = l >> 4;
  const int fg4 = fg * 4;
  const int qbase = qt * 64 + w * 16;
  const int qg = qbase + fr;
  const int qcol = h * HD;
  const int kcol = DM + h * HD;
  const int vcol = 2 * DM + h * HD;
  const float scale = 0.08838834764831845f;  // 1/sqrt(128)

  // Q fragments (B-operand: lane holds Q[qbase+fr][kt*32 + fg*8 .. +8])
  bf16x8 bq[4];
#pragma unroll
  for (int kt = 0; kt < 4; kt++)
    bq[kt] = *(const bf16x8*)&QKV[(size_t)(qbase + fr) * LDQ + qcol + kt * 32 + fg * 8];

  // per-lane K source base (A-operand rows kv0+kb*16+fr)
  const bf16* kbase = QKV + (size_t)fr * LDQ + kcol + fg * 8;
  // per-lane V stage source base (lane l -> row l>>1, col half l&1)
  const bf16* vbase = QKV + (size_t)(l >> 1) * LDQ + vcol + (l & 1) * 8;
  const unsigned ldsb = lds_addr(&Vs[0][0]) + 8u * (unsigned)l;

  f32x4 oacc[8] = {};
  float m = -1e30f, lsum = 0.f;

  // prologue: stage V tile 0
  {
    const int i0 = w * 4;
#pragma unroll
    for (int c = 0; c < 4; c++) {
      const int i = i0 + c, db = i >> 1, k0 = (i & 1) * 32;
      gload_lds16(vbase + (size_t)k0 * LDQ + db * 16, &Vs[0][db * 1024 + k0 * 16]);
    }
  }
  __syncthreads();

  for (int t = 0; t <= qt; ++t) {
    const int kv0 = t * 64;
    const int cur = t & 1;
    // ---- stage V tile t+1 into other buffer (flies under compute) ----
    if (t < qt) {
      const int kv1 = kv0 + 64;
      const int i0 = w * 4;
#pragma unroll
      for (int c = 0; c < 4; c++) {
        const int i = i0 + c, db = i >> 1, k0 = (i & 1) * 32;
        gload_lds16(vbase + (size_t)(kv1 + k0) * LDQ + db * 16,
                    &Vs[cur ^ 1][db * 1024 + k0 * 16]);
      }
    }
    // ---- K loads (direct global/L2) ----
    bf16x8 ak[4][4];
#pragma unroll
    for (int kb = 0; kb < 4; kb++)
#pragma unroll
      for (int kt = 0; kt < 4; kt++)
        ak[kb][kt] = *(const bf16x8*)(kbase + (size_t)(kv0 + kb * 16) * LDQ + kt * 32);
    // ---- QK^T (swapped): sacc[kb] holds S^T[k=kv0+kb*16+fg*4+j][q=fr] ----
    f32x4 sacc[4] = {};
#pragma unroll
    for (int kb = 0; kb < 4; kb++)
#pragma unroll
      for (int kt = 0; kt < 4; kt++)
        sacc[kb] = __builtin_amdgcn_mfma_f32_16x16x32_bf16(ak[kb][kt], bq[kt], sacc[kb], 0, 0, 0);
    // ---- online softmax (reduce over k: 16 regs + 2 shfl) ----
    const bool diag = (t == qt);
    float p[4][4];
    float tmax = -1e30f;
#pragma unroll
    for (int kb = 0; kb < 4; kb++)
#pragma unroll
      for (int j = 0; j < 4; j++) {
        float s = sacc[kb][j] * scale;
        if (diag && (kv0 + kb * 16 + fg4 + j) > qg) s = -1e30f;
        p[kb][j] = s;
        tmax = fmaxf(tmax, s);
      }
    tmax = fmaxf(tmax, __shfl_xor(tmax, 16, 64));
    tmax = fmaxf(tmax, __shfl_xor(tmax, 32, 64));
    const float mnew = fmaxf(m, tmax);
    const float alpha = __expf(m - mnew);
    m = mnew;
    float sum = 0.f;
#pragma unroll
    for (int kb = 0; kb < 4; kb++)
#pragma unroll
      for (int j = 0; j < 4; j++) {
        const float e = __expf(p[kb][j] - m);
        p[kb][j] = e;
        sum += e;
      }
    sum += __shfl_xor(sum, 16, 64);
    sum += __shfl_xor(sum, 32, 64);
    lsum = lsum * alpha + sum;
    float alpha4[4];
#pragma unroll
    for (int j = 0; j < 4; j++) alpha4[j] = __shfl(alpha, fg4 + j, 64);
#pragma unroll
    for (int db = 0; db < 8; db++)
#pragma unroll
      for (int j = 0; j < 4; j++) oacc[db][j] *= alpha4[j];
    // ---- pack P to bf16 A-fragments (consistent permutation, no cross-lane) ----
    bf16x8 pa[2];
#pragma unroll
    for (int kc = 0; kc < 2; kc++)
#pragma unroll
      for (int e = 0; e < 8; e++) pa[kc][e] = (bf16)p[2 * kc + (e >> 2)][e & 3];
    // ---- PV: V via tr_read, 2-deep pipelined ----
    {
      const unsigned va = ldsb + (unsigned)cur * 16384u;
      u32x2 ta[4], tb[4];
      TR4(ta, va);
#pragma unroll
      for (int db = 0; db < 8; db++) {
        const u32x2* curp = (db & 1) ? tb : ta;
        u32x2* nxtp = (db & 1) ? ta : tb;
        if (db < 7) {
          const unsigned vd = va + (unsigned)(db + 1) * 2048u;
          TR4(nxtp, vd);
          asm volatile("s_waitcnt lgkmcnt(4)" ::: "memory");
        } else {
          asm volatile("s_waitcnt lgkmcnt(0)" ::: "memory");
        }
        __builtin_amdgcn_sched_barrier(0);
        union { u32x2 h[2]; bf16x8 v; } u0, u1;
        u0.h[0] = curp[0]; u0.h[1] = curp[1];
        u1.h[0] = curp[2]; u1.h[1] = curp[3];
        oacc[db] = __builtin_amdgcn_mfma_f32_16x16x32_bf16(pa[0], u0.v, oacc[db], 0, 0, 0);
        oacc[db] = __builtin_amdgcn_mfma_f32_16x16x32_bf16(pa[1], u1.v, oacc[db], 0, 0, 0);
      }
    }
    __syncthreads();  // stage(t+1) drained; all waves done reading buf[cur]
  }

  // ---- epilogue: normalize, fused gate GEMM (reuses Q frags), store bf16 ----
  const float rinv = 1.0f / lsum;
  float rinv4[4];
#pragma unroll
  for (int j = 0; j < 4; j++) rinv4[j] = __shfl(rinv, fg4 + j, 64);
  f32x4 gacc[8] = {};
#pragma unroll
  for (int kt = 0; kt < 4; kt++)
#pragma unroll
    for (int eb = 0; eb < 8; eb++) {
      const bf16x8 bg = *(const bf16x8*)&GWb[(eb * 16 + fr) * HD + kt * 32 + fg * 8];
      gacc[eb] = __builtin_amdgcn_mfma_f32_16x16x32_bf16(bq[kt], bg, gacc[eb], 0, 0, 0);
    }
#pragma unroll
  for (int db = 0; db < 8; db++) {
    const int e = db * 16 + fr;
    const float bias = gbias[e];
    const int col = h * HD + e;
#pragma unroll
    for (int j = 0; j < 4; j++) {
      const float gate = 1.0f / (1.0f + __expf(-(gacc[db][j] + bias)));
      const float o = oacc[db][j] * rinv * 0.f + oacc[db][j] * rinv4[j] * gate;  // rinv kept live; use rinv4
      Gout[(size_t)(qbase + fg4 + j) * DM + col] = (bf16)o;
    }
  }
}

extern "C" void kernel_launch(void* const* d_in, const int* in_sizes, int n_in,
                              void* d_out, int out_size, void* d_ws, size_t ws_size,
                              hipStream_t stream) {
  const float* x  = (const float*)d_in[0];
  const float* qw = (const float*)d_in[1];
  const float* kw = (const float*)d_in[2];
  const float* vw = (const float*)d_in[3];
  const float* ow = (const float*)d_in[4];
  const float* gw = (const float*)d_in[5];
  const float* gb = (const float*)d_in[6];
  float* out = (float*)d_out;

  char* ws = (char*)d_ws;
  const size_t MB = 1024 * 1024;
  bf16* xb  = (bf16*)(ws + 0 * MB);    // 8 MB
  bf16* w3b = (bf16*)(ws + 8 * MB);    // 24 MB (qw,kw,vw rows 0/2048/4096)
  bf16* owb = (bf16*)(ws + 32 * MB);   // 8 MB
  bf16* gwb = (bf16*)(ws + 40 * MB);   // 32 KB
  bf16* QKV = (bf16*)(ws + 41 * MB);   // 24 MB  [2048][6144]
  bf16* Gb  = (bf16*)(ws + 65 * MB);   // 8 MB   [2048][2048]

  cvt6<<<dim3(4096, 6), 256, 0, stream>>>(x, qw, kw, vw, ow, gw,
                                          (ushort*)xb, (ushort*)w3b,
                                          (ushort*)owb, (ushort*)gwb);

  // fused QKV projection: C[2048][6144]
  gemm128<bf16><<<dim3(48, 16), 256, 0, stream>>>(xb, w3b, QKV, LDQ);

  attn_k<<<dim3(32, NH), 256, 0, stream>>>(QKV, gwb, gb, Gb);

  gemm128<float><<<dim3(16, 16), 256, 0, stream>>>(Gb, owb, out, DM);
}

// Round 3
// 176.922 us; speedup vs baseline: 2.3194x; 1.5628x over previous
//
#include <hip/hip_runtime.h>
#include <stdint.h>
#include <math.h>

#define DM 2048
#define NH 16
#define HD 128
#define LDQ (3 * DM)   // fused QKV row stride

typedef __bf16 bf16;
typedef __attribute__((ext_vector_type(8))) __bf16 bf16x8;
typedef __attribute__((ext_vector_type(4))) float f32x4;
typedef __attribute__((ext_vector_type(2))) unsigned int u32x2;

__device__ __forceinline__ void gload_lds16(const void* g, void* l) {
  __builtin_amdgcn_global_load_lds(
      (const __attribute__((address_space(1))) void*)g,
      (__attribute__((address_space(3))) void*)l,
      16, 0, 0);
}

__device__ __forceinline__ unsigned lds_addr(const void* p) {
  return (unsigned)(size_t)(const __attribute__((address_space(3))) void*)p;
}

template <int OFF>
__device__ __forceinline__ u32x2 tr_read(unsigned va) {
  u32x2 r;
  asm volatile("ds_read_b64_tr_b16 %0, %1 offset:%2"
               : "=v"(r) : "v"(va), "i"(OFF));
  return r;
}

#define TR4(dst, vd)                                        \
  dst[0] = tr_read<0>(vd);   dst[1] = tr_read<512>(vd);     \
  dst[2] = tr_read<1024>(vd); dst[3] = tr_read<1536>(vd);

// ---------------- fp32 -> bf16 conversion (all inputs, one launch) ----------------
__global__ __launch_bounds__(256) void cvt6(const float* xs, const float* qws,
                                            const float* kws, const float* vws,
                                            const float* ows, const float* gws,
                                            ushort* xd, ushort* w3d, ushort* owd,
                                            ushort* gwd) {
  const int y = blockIdx.y;
  const float4* s; ushort4* d; int n = (DM * DM) / 4;
  switch (y) {
    case 0: s = (const float4*)xs;  d = (ushort4*)xd;  break;
    case 1: s = (const float4*)qws; d = (ushort4*)w3d; break;
    case 2: s = (const float4*)kws; d = (ushort4*)(w3d + (size_t)DM * DM); break;
    case 3: s = (const float4*)vws; d = (ushort4*)(w3d + (size_t)2 * DM * DM); break;
    case 4: s = (const float4*)ows; d = (ushort4*)owd; break;
    default: s = (const float4*)gws; d = (ushort4*)gwd; n = (HD * HD) / 4; break;
  }
  int i = blockIdx.x * 256 + threadIdx.x;
  if (i >= n) return;
  float4 v = s[i];
  union { bf16 b[4]; ushort4 u; } r;
  r.b[0] = (bf16)v.x; r.b[1] = (bf16)v.y; r.b[2] = (bf16)v.z; r.b[3] = (bf16)v.w;
  d[i] = r.u;
}

// ---------------- GEMM: C[M,Ncols] = A[M,2048] * B[Ncols,2048]^T ----------------
template <typename OutT>
__global__ __launch_bounds__(256) void gemm128(const bf16* __restrict__ A,
                                               const bf16* __restrict__ Bw,
                                               OutT* __restrict__ C, int ldc) {
  __shared__ __align__(16) bf16 As[128 * 32];
  __shared__ __align__(16) bf16 Bs[128 * 32];
  const int tid = threadIdx.x;
  const int w = tid >> 6, l = tid & 63;
  const int wr = w >> 1, wc = w & 1;
  const int bx = blockIdx.x, by = blockIdx.y;
  const int lrow = l >> 2, lcol = (l & 3) * 8;
  const int fr = l & 15, fg = l >> 4;
  const bf16* Ag = A + (size_t)(by * 128 + w * 32 + lrow) * DM + lcol;
  const bf16* Bg = Bw + (size_t)(bx * 128 + w * 32 + lrow) * DM + lcol;
  bf16* Asw = &As[(w * 32) * 32];
  bf16* Bsw = &Bs[(w * 32) * 32];
  f32x4 acc[4][4] = {};
  for (int kt = 0; kt < DM / 32; ++kt) {
    const int ko = kt * 32;
    gload_lds16(Ag + ko, Asw);
    gload_lds16(Ag + ko + 16 * DM, Asw + 16 * 32);
    gload_lds16(Bg + ko, Bsw);
    gload_lds16(Bg + ko + 16 * DM, Bsw + 16 * 32);
    __syncthreads();
    bf16x8 af[4], bfr[4];
#pragma unroll
    for (int m = 0; m < 4; m++)
      af[m] = *(const bf16x8*)&As[(wr * 64 + m * 16 + fr) * 32 + fg * 8];
#pragma unroll
    for (int n = 0; n < 4; n++)
      bfr[n] = *(const bf16x8*)&Bs[(wc * 64 + n * 16 + fr) * 32 + fg * 8];
#pragma unroll
    for (int m = 0; m < 4; m++)
#pragma unroll
      for (int n = 0; n < 4; n++)
        acc[m][n] = __builtin_amdgcn_mfma_f32_16x16x32_bf16(af[m], bfr[n], acc[m][n], 0, 0, 0);
    __syncthreads();
  }
#pragma unroll
  for (int m = 0; m < 4; m++) {
    const int row0 = by * 128 + wr * 64 + m * 16 + fg * 4;
#pragma unroll
    for (int n = 0; n < 4; n++) {
      const int col = bx * 128 + wc * 64 + n * 16 + fr;
#pragma unroll
      for (int j = 0; j < 4; j++) C[(size_t)(row0 + j) * ldc + col] = (OutT)acc[m][n][j];
    }
  }
}

// ---------------- causal flash attention + fused sigmoid gate ----------------
// swapped QK^T (S^T in regs), in-register P, K in LDS (XOR-swizzled),
// V in LDS subtiled for ds_read_b64_tr_b16; both double-buffered, staged once
// per block via global_load_lds; 2-phase pipeline (stage t+1 during compute t).
// grid 512 linear: head = gid&15, idx = gid>>4, qt complementary-paired.
__global__ __launch_bounds__(256, 2) void attn_k(const bf16* __restrict__ QKV,
                                                 const bf16* __restrict__ GWb,
                                                 const float* __restrict__ gbias,
                                                 bf16* __restrict__ Gout) {
  __shared__ __align__(16) bf16 Ks[2][8192];  // [buf][64 k][128 d] XOR-swizzled (16B units)
  __shared__ __align__(16) bf16 Vs[2][8192];  // [buf][8 dblk][64 k][16 d]
  const int gid = blockIdx.x;
  const int h = gid & 15;
  const int idx = gid >> 4;
  const int qt = (idx < 16) ? (31 - idx) : (idx - 16);  // complementary pairs per CU
  const int tid = threadIdx.x;
  const int w = tid >> 6, l = tid & 63;
  const int fr = l & 15, fg = l >> 4;
  const int fg4 = fg * 4;
  const int qbase = qt * 64 + w * 16;
  const int qg = qbase + fr;
  const int qcol = h * HD;
  const int kcol = DM + h * HD;
  const int vcol = 2 * DM + h * HD;
  const float scale = 0.08838834764831845f;  // 1/sqrt(128)

  // Q fragments (B-operand)
  bf16x8 bq[4];
#pragma unroll
  for (int kt = 0; kt < 4; kt++)
    bq[kt] = *(const bf16x8*)&QKV[(size_t)(qbase + fr) * LDQ + qcol + kt * 32 + fg * 8];

  // per-lane V stage source base (lane l -> k row l>>1, col half l&1)
  const bf16* vbase = QKV + (size_t)(l >> 1) * LDQ + vcol + (l & 1) * 8;
  bf16* Ksl = &Ks[0][0];
  bf16* Vsl = &Vs[0][0];
  const unsigned ldsb = lds_addr(Vsl) + 8u * (unsigned)l;

  // stage K tile (linear dest, inverse-swizzled source) + V tile (subtiled)
#define STAGE(buf, kvbase)                                                    \
  {                                                                           \
    _Pragma("unroll")                                                         \
    for (int c = 0; c < 4; c++) {                                             \
      const int i = w * 4 + c;                                                \
      const int krow = i * 4 + (l >> 4);                                      \
      const int c16 = (l & 15) ^ (krow & 7);                                  \
      gload_lds16(QKV + (size_t)((kvbase) + krow) * LDQ + kcol + c16 * 8,     \
                  Ksl + (buf) * 8192 + i * 512);                              \
      const int db = i >> 1, k0 = (i & 1) * 32;                               \
      gload_lds16(vbase + (size_t)((kvbase) + k0) * LDQ + db * 16,            \
                  Vsl + (buf) * 8192 + db * 1024 + k0 * 16);                  \
    }                                                                         \
  }

  f32x4 oacc[8] = {};
  float m = -1e30f, lsum = 0.f;

  STAGE(0, 0);
  __syncthreads();  // drains vmcnt(0); tile 0 resident

  for (int t = 0; t <= qt; ++t) {
    const int kv0 = t * 64;
    const int cur = t & 1;
    // ---- K fragments from LDS (swizzled read) — BEFORE stage issue ----
    bf16x8 ak[4][4];
    {
      const char* Kb = (const char*)(Ksl + cur * 8192);
      const int swz = fr & 7;
#pragma unroll
      for (int kb = 0; kb < 4; kb++) {
        const char* rp = Kb + (kb * 16 + fr) * 256;
#pragma unroll
        for (int kt = 0; kt < 4; kt++)
          ak[kb][kt] = *(const bf16x8*)(rp + (((kt * 4 + fg) ^ swz) << 4));
      }
    }
    // ---- stage tile t+1 into other buffer (drained only at end barrier) ----
    if (t < qt) STAGE(cur ^ 1, kv0 + 64);
    // ---- QK^T (swapped): sacc[kb] holds S^T[k][q=fr] ----
    f32x4 sacc[4] = {};
#pragma unroll
    for (int kb = 0; kb < 4; kb++)
#pragma unroll
      for (int kt = 0; kt < 4; kt++)
        sacc[kb] = __builtin_amdgcn_mfma_f32_16x16x32_bf16(ak[kb][kt], bq[kt], sacc[kb], 0, 0, 0);
    // ---- online softmax (reduce over k: 16 regs + 2 shfl) ----
    const bool diag = (t == qt);
    float p[4][4];
    float tmax = -1e30f;
#pragma unroll
    for (int kb = 0; kb < 4; kb++)
#pragma unroll
      for (int j = 0; j < 4; j++) {
        float s = sacc[kb][j] * scale;
        if (diag && (kv0 + kb * 16 + fg4 + j) > qg) s = -1e30f;
        p[kb][j] = s;
        tmax = fmaxf(tmax, s);
      }
    tmax = fmaxf(tmax, __shfl_xor(tmax, 16, 64));
    tmax = fmaxf(tmax, __shfl_xor(tmax, 32, 64));
    const float mnew = fmaxf(m, tmax);
    const float alpha = __expf(m - mnew);
    m = mnew;
    float sum = 0.f;
#pragma unroll
    for (int kb = 0; kb < 4; kb++)
#pragma unroll
      for (int j = 0; j < 4; j++) {
        const float e = __expf(p[kb][j] - m);
        p[kb][j] = e;
        sum += e;
      }
    sum += __shfl_xor(sum, 16, 64);
    sum += __shfl_xor(sum, 32, 64);
    lsum = lsum * alpha + sum;
    float alpha4[4];
#pragma unroll
    for (int j = 0; j < 4; j++) alpha4[j] = __shfl(alpha, fg4 + j, 64);
#pragma unroll
    for (int db = 0; db < 8; db++)
#pragma unroll
      for (int j = 0; j < 4; j++) oacc[db][j] *= alpha4[j];
    // ---- pack P to bf16 A-fragments (consistent permutation, no cross-lane) ----
    bf16x8 pa[2];
#pragma unroll
    for (int kc = 0; kc < 2; kc++)
#pragma unroll
      for (int e = 0; e < 8; e++) pa[kc][e] = (bf16)p[2 * kc + (e >> 2)][e & 3];
    // ---- PV: V via tr_read, 2-deep pipelined ----
    {
      const unsigned va = ldsb + (unsigned)cur * 16384u;
      u32x2 ta[4], tb[4];
      TR4(ta, va);
#pragma unroll
      for (int db = 0; db < 8; db++) {
        const u32x2* curp = (db & 1) ? tb : ta;
        u32x2* nxtp = (db & 1) ? ta : tb;
        if (db < 7) {
          const unsigned vd = va + (unsigned)(db + 1) * 2048u;
          TR4(nxtp, vd);
          asm volatile("s_waitcnt lgkmcnt(4)" ::: "memory");
        } else {
          asm volatile("s_waitcnt lgkmcnt(0)" ::: "memory");
        }
        __builtin_amdgcn_sched_barrier(0);
        union { u32x2 h[2]; bf16x8 v; } u0, u1;
        u0.h[0] = curp[0]; u0.h[1] = curp[1];
        u1.h[0] = curp[2]; u1.h[1] = curp[3];
        oacc[db] = __builtin_amdgcn_mfma_f32_16x16x32_bf16(pa[0], u0.v, oacc[db], 0, 0, 0);
        oacc[db] = __builtin_amdgcn_mfma_f32_16x16x32_bf16(pa[1], u1.v, oacc[db], 0, 0, 0);
      }
    }
    __syncthreads();  // drains stage(t+1) vmcnt + all waves done with buf[cur]
  }

  // ---- epilogue: normalize, fused gate GEMM (reuses Q frags), store bf16 ----
  const float rinv = 1.0f / lsum;
  float rinv4[4];
#pragma unroll
  for (int j = 0; j < 4; j++) rinv4[j] = __shfl(rinv, fg4 + j, 64);
  f32x4 gacc[8] = {};
#pragma unroll
  for (int kt = 0; kt < 4; kt++)
#pragma unroll
    for (int eb = 0; eb < 8; eb++) {
      const bf16x8 bg = *(const bf16x8*)&GWb[(eb * 16 + fr) * HD + kt * 32 + fg * 8];
      gacc[eb] = __builtin_amdgcn_mfma_f32_16x16x32_bf16(bq[kt], bg, gacc[eb], 0, 0, 0);
    }
#pragma unroll
  for (int db = 0; db < 8; db++) {
    const int e = db * 16 + fr;
    const float bias = gbias[e];
    const int col = h * HD + e;
#pragma unroll
    for (int j = 0; j < 4; j++) {
      const float gate = 1.0f / (1.0f + __expf(-(gacc[db][j] + bias)));
      const float o = oacc[db][j] * rinv4[j] * gate;
      Gout[(size_t)(qbase + fg4 + j) * DM + col] = (bf16)o;
    }
  }
#undef STAGE
}

extern "C" void kernel_launch(void* const* d_in, const int* in_sizes, int n_in,
                              void* d_out, int out_size, void* d_ws, size_t ws_size,
                              hipStream_t stream) {
  const float* x  = (const float*)d_in[0];
  const float* qw = (const float*)d_in[1];
  const float* kw = (const float*)d_in[2];
  const float* vw = (const float*)d_in[3];
  const float* ow = (const float*)d_in[4];
  const float* gw = (const float*)d_in[5];
  const float* gb = (const float*)d_in[6];
  float* out = (float*)d_out;

  char* ws = (char*)d_ws;
  const size_t MB = 1024 * 1024;
  bf16* xb  = (bf16*)(ws + 0 * MB);    // 8 MB
  bf16* w3b = (bf16*)(ws + 8 * MB);    // 24 MB (qw,kw,vw rows 0/2048/4096)
  bf16* owb = (bf16*)(ws + 32 * MB);   // 8 MB
  bf16* gwb = (bf16*)(ws + 40 * MB);   // 32 KB
  bf16* QKV = (bf16*)(ws + 41 * MB);   // 24 MB  [2048][6144]
  bf16* Gb  = (bf16*)(ws + 65 * MB);   // 8 MB   [2048][2048]

  cvt6<<<dim3(4096, 6), 256, 0, stream>>>(x, qw, kw, vw, ow, gw,
                                          (ushort*)xb, (ushort*)w3b,
                                          (ushort*)owb, (ushort*)gwb);

  // fused QKV projection: C[2048][6144]
  gemm128<bf16><<<dim3(48, 16), 256, 0, stream>>>(xb, w3b, QKV, LDQ);

  attn_k<<<512, 256, 0, stream>>>(QKV, gwb, gb, Gb);

  gemm128<float><<<dim3(16, 16), 256, 0, stream>>>(Gb, owb, out, DM);
}